// Round 1
// baseline (104.857 us; speedup 1.0000x reference)
//
#include <hip/hip_runtime.h>
#include <hip/hip_cooperative_groups.h>
#include <math.h>

namespace cg = cooperative_groups;

#define NROWS 2048
#define MCOLS 32
#define NBLK  64      // cooperative grid: 64 blocks x 256 threads, 4 elems/thread
#define TPB   256
#define ELEMS 4

// Taylor erf on |x| <= ~0.354: erf(x) = c1 x + c3 x^3 + c5 x^5 + c7 x^7
#define C1 1.1283791671f
#define C3 (-0.3761263890f)
#define C5 0.1128379167f
#define C7 (-0.0268661706f)

// Single fused cooperative kernel.
// Phase A: t=exp(expr-tr), e=exp(risk) kept in REGISTERS; per-block column max
//          and per-block unscaled moment partials M'_q[k] = sum_a e*t^q -> global.
// grid.sync()
// Phase B: (redundant per block, cheap) reduce partials, compute scale s,
//          binomial Horner coefficients D_0..7, 0.5*S -> LDS.
// Phase C: per element Horner + log, block reduce, one atomicAdd per block.
__global__ __launch_bounds__(TPB) void k_fused(const float* __restrict__ risk,
                                               const float* __restrict__ expr,
                                               const float* __restrict__ tr,
                                               const float* __restrict__ event,
                                               const float* __restrict__ sigma,
                                               float* __restrict__ partM,    // [NBLK*256]
                                               float* __restrict__ partMax,  // [NBLK*32]
                                               float* __restrict__ out) {
    cg::grid_group grid = cg::this_grid();
    const int tid = threadIdx.x;
    const int bid = blockIdx.x;
    const int k = tid & 31;
    const int q = tid >> 5;          // 0..7

    if (bid == 0 && tid == 0) out[0] = 0.0f;   // ordered before phase-C atomics by grid.sync

    __shared__ float sm_t[TPB];
    __shared__ float sm_e[TPB];

    float tv[ELEMS], ev[ELEMS], rk[ELEMS];
    float partial = 0.0f, mx = 0.0f;

#pragma unroll
    for (int r = 0; r < ELEMS; r++) {
        const int i = (bid * ELEMS + r) * TPB + tid;   // i = a*32 + k, row-major
        const float rv = risk[i];
        tv[r] = __expf(expr[i] - tr[i]);
        ev[r] = __expf(rv);
        rk[r] = rv;

        sm_t[tid] = tv[r];
        sm_e[tid] = ev[r];
        __syncthreads();
#pragma unroll
        for (int row = 0; row < 8; row++) {
            const float t = sm_t[row * 32 + k];
            const float e = sm_e[row * 32 + k];
            float p = e;
            for (int m = 0; m < q; m++) p *= t;        // e * t^q
            partial += p;
            mx = fmaxf(mx, t);
        }
        __syncthreads();
    }
    partM[bid * 256 + tid] = partial;          // tid == q*32+k
    if (q == 0) partMax[bid * 32 + k] = mx;    // t>0 always

    grid.sync();

    // ---- Phase B: reduce partials + build coefficients (redundant per block) ----
    __shared__ float sM[256];
    __shared__ float sMax[32];
    {
        float msum = 0.0f;
#pragma unroll
        for (int b = 0; b < NBLK; b++) msum += partM[b * 256 + tid];
        sM[tid] = msum;
        if (q == 0) {
            float m2 = 0.0f;
#pragma unroll
            for (int b = 0; b < NBLK; b++) m2 = fmaxf(m2, partMax[b * 32 + k]);
            sMax[k] = m2;
        }
    }
    __syncthreads();

    __shared__ float sD[256];
    __shared__ float sSc[32];
    __shared__ float sSh[32];
    {
        const float s = 1.0f / (sMax[k] * 2.0f * sigma[0] * sqrtf(2.0f));
        float M[8];
        float sp = 1.0f;
#pragma unroll
        for (int j = 0; j < 8; j++) { M[j] = sM[j * 32 + k] * sp; sp *= s; }
        float d;
        if      (q == 0) d = C1 * M[1] +         C3 * M[3] +         C5 * M[5] +        C7 * M[7];
        else if (q == 1) d = C1 * M[0] + 3.0f *  C3 * M[2] + 5.0f *  C5 * M[4] + 7.0f * C7 * M[6];
        else if (q == 2) d = 3.0f * C3 * M[1] + 10.0f * C5 * M[3] + 21.0f * C7 * M[5];
        else if (q == 3) d = C3 * M[0] + 10.0f * C5 * M[2] + 35.0f * C7 * M[4];
        else if (q == 4) d = 5.0f * C5 * M[1] + 35.0f * C7 * M[3];
        else if (q == 5) d = C5 * M[0] + 21.0f * C7 * M[2];
        else if (q == 6) d = 7.0f * C7 * M[1];
        else             d = C7 * M[0];
        sD[tid] = d;
        if (q == 0) { sSc[k] = s; sSh[k] = 0.5f * M[0]; }
    }
    __syncthreads();

    // ---- Phase C: Horner + log + reduce ----
    float csum = 0.0f;
    const float sck = sSc[k];
    const float shk = sSh[k];
#pragma unroll
    for (int r = 0; r < ELEMS; r++) {
        const int i = (bid * ELEMS + r) * TPB + tid;
        const float w = -(tv[r] * sck);
        float acc = sD[7 * 32 + k];
#pragma unroll
        for (int p = 6; p >= 0; p--)
            acc = fmaf(acc, w, sD[p * 32 + k]);
        const float cum = shk + 0.5f * (acc + ev[r]);
        csum += (__logf(cum) - rk[r]) * event[i];
    }

    for (int off = 32; off > 0; off >>= 1)
        csum += __shfl_down(csum, off, 64);
    __shared__ float wsum[4];
    if ((tid & 63) == 0) wsum[tid >> 6] = csum;
    __syncthreads();
    if (tid == 0)
        atomicAdd(out, (wsum[0] + wsum[1]) + (wsum[2] + wsum[3]));
}

extern "C" void kernel_launch(void* const* d_in, const int* in_sizes, int n_in,
                              void* d_out, int out_size, void* d_ws, size_t ws_size,
                              hipStream_t stream) {
    const float* risk  = (const float*)d_in[0];
    const float* expr  = (const float*)d_in[1];
    const float* tr    = (const float*)d_in[2];
    const float* event = (const float*)d_in[3];
    const float* sigma = (const float*)d_in[4];
    float* out = (float*)d_out;

    float* partM   = (float*)d_ws;            // NBLK*256 floats
    float* partMax = partM + NBLK * 256;      // NBLK*32  floats

    void* args[] = {(void*)&risk, (void*)&expr, (void*)&tr, (void*)&event,
                    (void*)&sigma, (void*)&partM, (void*)&partMax, (void*)&out};
    hipLaunchCooperativeKernel((const void*)k_fused, dim3(NBLK), dim3(TPB),
                               args, 0, stream);
}

// Round 2
// 88.811 us; speedup vs baseline: 1.1807x; 1.1807x over previous
//
#include <hip/hip_runtime.h>
#include <math.h>

#define NROWS 2048
#define MCOLS 32
#define NBLK  64
#define TPB   1024
#define CHUNK ((NROWS * MCOLS) / TPB)   // 64 elements per thread

// Taylor erf on |x| <= ~0.354: erf(x) = c1 x + c3 x^3 + c5 x^5 + c7 x^7
#define C1 1.1283791671f
#define C3 (-0.3761263890f)
#define C5 0.1128379167f
#define C7 (-0.0268661706f)

// ONE regular kernel, zero inter-block communication.
// Every block redundantly computes the full moments M'_q[k] = sum_a e*t^q and
// column maxes (LDS reduce), the Horner coefficients D, the full phase-C sum,
// and plain-stores the identical final scalar. No atomics, no init, no ws.
__global__ __launch_bounds__(TPB) void k_all(const float* __restrict__ risk,
                                             const float* __restrict__ expr,
                                             const float* __restrict__ tr,
                                             const float* __restrict__ event,
                                             const float* __restrict__ sigma,
                                             float* __restrict__ out) {
    const int tid = threadIdx.x;
    const int k = tid & 31;    // column
    const int g = tid >> 5;    // row-group 0..31

    // ---- Phase A: per-thread moment partials over this thread's 64 rows ----
    float acc[8];
#pragma unroll
    for (int q = 0; q < 8; ++q) acc[q] = 0.0f;
    float mx = 0.0f;

#pragma unroll 4
    for (int c = 0; c < CHUNK; ++c) {
        const int i = c * TPB + tid;            // i = a*32 + k, coalesced
        const float tv = __expf(expr[i] - tr[i]);
        const float ev = __expf(risk[i]);
        mx = fmaxf(mx, tv);
        float p = ev;
#pragma unroll
        for (int q = 0; q < 8; ++q) { acc[q] += p; p *= tv; }
    }

    __shared__ float redM[32 * 256];   // [g][q*32+k]
    __shared__ float redX[32 * 32];    // [g][k]
#pragma unroll
    for (int q = 0; q < 8; ++q) redM[g * 256 + q * 32 + k] = acc[q];
    redX[g * 32 + k] = mx;
    __syncthreads();

    // ---- Reduce across the 32 row-groups ----
    __shared__ float sM[256];
    __shared__ float sMax[32];
    if (tid < 256) {
        float msum = 0.0f;
#pragma unroll
        for (int gg = 0; gg < 32; ++gg) msum += redM[gg * 256 + tid];
        sM[tid] = msum;
    }
    if (tid < 32) {
        float m2 = 0.0f;
#pragma unroll
        for (int gg = 0; gg < 32; ++gg) m2 = fmaxf(m2, redX[gg * 32 + tid]);
        sMax[tid] = m2;
    }
    __syncthreads();

    // ---- Coefficients: per column, scale s, scaled moments, binomial Horner D ----
    __shared__ float sD[256];
    __shared__ float sSc[32];
    __shared__ float sSh[32];
    if (tid < 32) {
        const float s = 1.0f / (sMax[tid] * 2.0f * sigma[0] * sqrtf(2.0f));
        float M[8];
        float sp = 1.0f;
#pragma unroll
        for (int q = 0; q < 8; ++q) { M[q] = sM[q * 32 + tid] * sp; sp *= s; }
        sD[0 * 32 + tid] = C1 * M[1] +          C3 * M[3] +          C5 * M[5] +         C7 * M[7];
        sD[1 * 32 + tid] = C1 * M[0] + 3.0f  * C3 * M[2] + 5.0f  * C5 * M[4] + 7.0f * C7 * M[6];
        sD[2 * 32 + tid] = 3.0f * C3 * M[1] + 10.0f * C5 * M[3] + 21.0f * C7 * M[5];
        sD[3 * 32 + tid] = C3 * M[0] + 10.0f * C5 * M[2] + 35.0f * C7 * M[4];
        sD[4 * 32 + tid] = 5.0f * C5 * M[1] + 35.0f * C7 * M[3];
        sD[5 * 32 + tid] = C5 * M[0] + 21.0f * C7 * M[2];
        sD[6 * 32 + tid] = 7.0f * C7 * M[1];
        sD[7 * 32 + tid] = C7 * M[0];
        sSc[tid] = s;
        sSh[tid] = 0.5f * M[0];
    }
    __syncthreads();

    // ---- Phase C: full redundant Horner + log over all elements ----
    const float sck = sSc[k];
    const float shk = sSh[k];
    const float d0 = sD[0 * 32 + k], d1 = sD[1 * 32 + k], d2 = sD[2 * 32 + k],
                d3 = sD[3 * 32 + k], d4 = sD[4 * 32 + k], d5 = sD[5 * 32 + k],
                d6 = sD[6 * 32 + k], d7 = sD[7 * 32 + k];
    float csum = 0.0f;
#pragma unroll 4
    for (int c = 0; c < CHUNK; ++c) {
        const int i = c * TPB + tid;
        const float rv = risk[i];
        const float tv = __expf(expr[i] - tr[i]);
        const float ev = __expf(rv);
        const float w = -(tv * sck);
        float a = d7;
        a = fmaf(a, w, d6);
        a = fmaf(a, w, d5);
        a = fmaf(a, w, d4);
        a = fmaf(a, w, d3);
        a = fmaf(a, w, d2);
        a = fmaf(a, w, d1);
        a = fmaf(a, w, d0);
        const float cum = shk + 0.5f * (a + ev);
        csum += (__logf(cum) - rv) * event[i];
    }

    // ---- Deterministic block reduction (identical in every block) ----
    for (int off = 32; off > 0; off >>= 1)
        csum += __shfl_down(csum, off, 64);
    __shared__ float wsum[TPB / 64];
    if ((tid & 63) == 0) wsum[tid >> 6] = csum;
    __syncthreads();
    if (tid == 0) {
        float s = 0.0f;
#pragma unroll
        for (int w2 = 0; w2 < TPB / 64; ++w2) s += wsum[w2];
        out[0] = s;   // every block stores the same bits: benign race
    }
}

extern "C" void kernel_launch(void* const* d_in, const int* in_sizes, int n_in,
                              void* d_out, int out_size, void* d_ws, size_t ws_size,
                              hipStream_t stream) {
    const float* risk  = (const float*)d_in[0];
    const float* expr  = (const float*)d_in[1];
    const float* tr    = (const float*)d_in[2];
    const float* event = (const float*)d_in[3];
    const float* sigma = (const float*)d_in[4];
    float* out = (float*)d_out;

    k_all<<<dim3(NBLK), dim3(TPB), 0, stream>>>(risk, expr, tr, event, sigma, out);
}

// Round 3
// 75.861 us; speedup vs baseline: 1.3822x; 1.1707x over previous
//
#include <hip/hip_runtime.h>
#include <math.h>

#define NROWS 2048
#define MCOLS 32
#define ABLK  64      // kernel A: 64 blocks x 256 threads x 4 elems
#define BBLK  256     // kernel B: 256 blocks x 256 threads x 1 elem

// Taylor erf on |x| <= ~0.354: erf(x) = c1 x + c3 x^3 + c5 x^5 + c7 x^7
#define C1 1.1283791671f
#define C3 (-0.3761263890f)
#define C5 0.1128379167f
#define C7 (-0.0268661706f)

// Kernel A: per-block unscaled moment partials M'_q[k] = sum_a e*t^q (q=0..7)
// and per-block column max of t, plain-stored (no atomics, no init kernel).
// Thread (q,k) = (tid>>5, tid&31). Also zeroes out[0] for B's atomics.
__global__ __launch_bounds__(256) void k_mom(const float* __restrict__ expr,
                                             const float* __restrict__ tr,
                                             const float* __restrict__ risk,
                                             float* __restrict__ partM,   // [ABLK*256]
                                             float* __restrict__ partX,   // [ABLK*32]
                                             float* __restrict__ out) {
    const int tid = threadIdx.x;
    const int bid = blockIdx.x;
    if (bid == 0 && tid == 0) out[0] = 0.0f;   // visible to B via stream order

    __shared__ float sm_t[256];
    __shared__ float sm_e[256];
    const int k = tid & 31;
    const int q = tid >> 5;

    float partial = 0.0f, mx = 0.0f;
#pragma unroll
    for (int c = 0; c < 4; ++c) {
        const int i = (bid * 4 + c) * 256 + tid;   // i = a*32 + k, coalesced
        const float tv = __expf(expr[i] - tr[i]);
        const float ev = __expf(risk[i]);
        sm_t[tid] = tv;
        sm_e[tid] = ev;
        __syncthreads();
#pragma unroll
        for (int r = 0; r < 8; ++r) {
            const float t = sm_t[r * 32 + k];
            const float e = sm_e[r * 32 + k];
            float p = e;
            for (int m = 0; m < q; ++m) p *= t;    // e * t^q
            partial += p;
            mx = fmaxf(mx, t);
        }
        __syncthreads();
    }
    partM[bid * 256 + tid] = partial;
    if (q == 0) partX[bid * 32 + k] = mx;
}

// Kernel B: redundant per-block reduce of the tiny partials (72 KB, L2-hot),
// coefficient build across all 256 threads, then full-parallel Horner+log,
// block reduce, one atomicAdd per block.
__global__ __launch_bounds__(256) void k_eval(const float* __restrict__ expr,
                                              const float* __restrict__ tr,
                                              const float* __restrict__ risk,
                                              const float* __restrict__ event,
                                              const float* __restrict__ sigma,
                                              const float* __restrict__ partM,
                                              const float* __restrict__ partX,
                                              float* __restrict__ out) {
    const int tid = threadIdx.x;
    const int bid = blockIdx.x;
    const int k = tid & 31;
    const int q = tid >> 5;

    // ---- reduce per-block partials (all 256 threads busy) ----
    __shared__ float sM[256];
    __shared__ float sMax[32];
    {
        float msum = 0.0f;
#pragma unroll
        for (int b = 0; b < ABLK; ++b) msum += partM[b * 256 + tid];
        sM[tid] = msum;
        if (tid < 32) {
            float m2 = 0.0f;
#pragma unroll
            for (int b = 0; b < ABLK; ++b) m2 = fmaxf(m2, partX[b * 32 + tid]);
            sMax[tid] = m2;
        }
    }
    __syncthreads();

    // ---- coefficients: thread (q,k) computes sD[q*32+k] ----
    __shared__ float sD[256];
    __shared__ float sSc[32];
    __shared__ float sSh[32];
    {
        const float s = 1.0f / (sMax[k] * 2.0f * sigma[0] * sqrtf(2.0f));
        float M[8];
        float sp = 1.0f;
#pragma unroll
        for (int j = 0; j < 8; ++j) { M[j] = sM[j * 32 + k] * sp; sp *= s; }
        float d;
        if      (q == 0) d = C1 * M[1] +         C3 * M[3] +         C5 * M[5] +        C7 * M[7];
        else if (q == 1) d = C1 * M[0] + 3.0f *  C3 * M[2] + 5.0f *  C5 * M[4] + 7.0f * C7 * M[6];
        else if (q == 2) d = 3.0f * C3 * M[1] + 10.0f * C5 * M[3] + 21.0f * C7 * M[5];
        else if (q == 3) d = C3 * M[0] + 10.0f * C5 * M[2] + 35.0f * C7 * M[4];
        else if (q == 4) d = 5.0f * C5 * M[1] + 35.0f * C7 * M[3];
        else if (q == 5) d = C5 * M[0] + 21.0f * C7 * M[2];
        else if (q == 6) d = 7.0f * C7 * M[1];
        else             d = C7 * M[0];
        sD[tid] = d;
        if (q == 0) { sSc[k] = s; sSh[k] = 0.5f * M[0]; }
    }
    __syncthreads();

    // ---- Horner + log, one element per thread ----
    const int i = bid * 256 + tid;     // i = j*32 + k
    const float rv = risk[i];
    const float tv = __expf(expr[i] - tr[i]);
    const float ev = __expf(rv);
    const float w = -(tv * sSc[k]);
    float a = sD[7 * 32 + k];
#pragma unroll
    for (int p = 6; p >= 0; --p)
        a = fmaf(a, w, sD[p * 32 + k]);
    const float cum = sSh[k] + 0.5f * (a + ev);
    float c = (__logf(cum) - rv) * event[i];

    // ---- block reduce + one atomic ----
    for (int off = 32; off > 0; off >>= 1)
        c += __shfl_down(c, off, 64);
    __shared__ float wsum[4];
    if ((tid & 63) == 0) wsum[tid >> 6] = c;
    __syncthreads();
    if (tid == 0)
        atomicAdd(out, (wsum[0] + wsum[1]) + (wsum[2] + wsum[3]));
}

extern "C" void kernel_launch(void* const* d_in, const int* in_sizes, int n_in,
                              void* d_out, int out_size, void* d_ws, size_t ws_size,
                              hipStream_t stream) {
    const float* risk  = (const float*)d_in[0];
    const float* expr  = (const float*)d_in[1];
    const float* tr    = (const float*)d_in[2];
    const float* event = (const float*)d_in[3];
    const float* sigma = (const float*)d_in[4];
    float* out = (float*)d_out;

    float* partM = (float*)d_ws;          // ABLK*256 floats
    float* partX = partM + ABLK * 256;    // ABLK*32 floats

    k_mom<<<dim3(ABLK), dim3(256), 0, stream>>>(expr, tr, risk, partM, partX, out);
    k_eval<<<dim3(BBLK), dim3(256), 0, stream>>>(expr, tr, risk, event, sigma,
                                                 partM, partX, out);
}